// Round 2
// baseline (780.981 us; speedup 1.0000x reference)
//
#include <hip/hip_runtime.h>
#include <stdint.h>

typedef unsigned short ushort_t;
typedef __bf16 bf16x8 __attribute__((ext_vector_type(8)));
typedef float f32x4 __attribute__((ext_vector_type(4)));

#define MFMA16(a, b, c) __builtin_amdgcn_mfma_f32_16x16x32_bf16((a), (b), (c), 0, 0, 0)

constexpr int Bn = 4, Sn = 2048, Dn = 1024, Hn = 16, HDn = 64;
constexpr float SCALE = 0.125f;   // 1/sqrt(64)
constexpr float NEG = -1e9f;

__device__ __forceinline__ float bf2f(ushort_t u) {
  unsigned x = ((unsigned)u) << 16;
  return __builtin_bit_cast(float, x);
}
__device__ __forceinline__ ushort_t f2bf(float f) {
  unsigned x = __builtin_bit_cast(unsigned, f);
  x = x + 0x7FFFu + ((x >> 16) & 1u);   // RNE
  return (ushort_t)(x >> 16);
}
// load 8 consecutive f32, round to bf16, return as 16B chunk for LDS store
__device__ __forceinline__ uint4 ld8_f32_bf16(const float* __restrict__ p) {
  float4 a = *(const float4*)p;
  float4 b = *(const float4*)(p + 4);
  union { ushort_t u[8]; uint4 v; } r;
  r.u[0] = f2bf(a.x); r.u[1] = f2bf(a.y); r.u[2] = f2bf(a.z); r.u[3] = f2bf(a.w);
  r.u[4] = f2bf(b.x); r.u[5] = f2bf(b.y); r.u[6] = f2bf(b.z); r.u[7] = f2bf(b.w);
  return r.v;
}

// C = A[M,K] @ W[N,K]^T + bias via MFMA 16x16x32 bf16, fp32 accum.
// A_BF16: A is bf16 (internal ws) else f32 (harness input, converted on stage).
// C_F32:  C is f32 row-major [M,N] (final proj -> d_out);
//         else bf16 scattered to [B,H,S,HD] head-major (Q/K/V).
template <bool A_BF16, bool C_F32>
__global__ __launch_bounds__(256)
void gemm_bt(const void* __restrict__ Ap, const float* __restrict__ Wt,
             const float* __restrict__ bias, void* __restrict__ Cp) {
  constexpr int K = 1024, N = 1024;
  __shared__ __align__(16) ushort_t As[128][72];
  __shared__ __align__(16) ushort_t Bs[128][72];

  const int tid = threadIdx.x;
  const int lane = tid & 63, w = tid >> 6;
  const int quad = lane >> 4, l16 = lane & 15;
  const int wm = w >> 1, wn = w & 1;
  const int row0 = blockIdx.y * 128;
  const int col0 = blockIdx.x * 128;

  f32x4 acc[4][4] = {};

  for (int k0 = 0; k0 < K; k0 += 64) {
    __syncthreads();
#pragma unroll
    for (int i = 0; i < 4; ++i) {          // stage 128x64 A and B tiles
      int c = tid + i * 256;
      int r = c >> 3, cc = (c & 7) * 8;
      if (A_BF16)
        *(uint4*)(&As[r][cc]) =
            *(const uint4*)((const ushort_t*)Ap + (size_t)(row0 + r) * K + k0 + cc);
      else
        *(uint4*)(&As[r][cc]) =
            ld8_f32_bf16((const float*)Ap + (size_t)(row0 + r) * K + k0 + cc);
      *(uint4*)(&Bs[r][cc]) = ld8_f32_bf16(Wt + (size_t)(col0 + r) * K + k0 + cc);
    }
    __syncthreads();
#pragma unroll
    for (int ks = 0; ks < 2; ++ks) {
      bf16x8 af[4], bfr[4];
#pragma unroll
      for (int mt = 0; mt < 4; ++mt)
        af[mt] = *(const bf16x8*)(&As[wm * 64 + mt * 16 + l16][ks * 32 + quad * 8]);
#pragma unroll
      for (int nt = 0; nt < 4; ++nt)
        bfr[nt] = *(const bf16x8*)(&Bs[wn * 64 + nt * 16 + l16][ks * 32 + quad * 8]);
#pragma unroll
      for (int mt = 0; mt < 4; ++mt)
#pragma unroll
        for (int nt = 0; nt < 4; ++nt)
          acc[mt][nt] = MFMA16(af[mt], bfr[nt], acc[mt][nt]);
    }
  }

  // epilogue: C/D layout col=lane&15, row=quad*4+reg (m89/m91-verified)
#pragma unroll
  for (int mt = 0; mt < 4; ++mt) {
#pragma unroll
    for (int nt = 0; nt < 4; ++nt) {
      int col = col0 + wn * 64 + nt * 16 + l16;
      float bv = bias[col];
#pragma unroll
      for (int r = 0; r < 4; ++r) {
        int row = row0 + wm * 64 + mt * 16 + quad * 4 + r;
        float outv = acc[mt][nt][r] + bv;
        if (C_F32) {
          ((float*)Cp)[(size_t)row * N + col] = outv;
        } else {
          int b = row >> 11, s = row & (Sn - 1);
          int h = col >> 6, hd = col & 63;
          ((ushort_t*)Cp)[(((size_t)(b * Hn + h) * Sn + s) << 6) + hd] = f2bf(outv);
        }
      }
    }
  }
}

// suffV[bh][t][n] = sum_{k >= (t+1)*128} V[bh][k][n]  (fp32; V is internal bf16)
__global__ __launch_bounds__(64)
void suffv_kernel(const ushort_t* __restrict__ V, float* __restrict__ suffV) {
  const int bh = blockIdx.x;   // 0..63
  const int t = blockIdx.y;    // 0..15
  const int n = threadIdx.x;   // 0..63
  const ushort_t* Vb = V + (size_t)bh * Sn * HDn;
  float acc = 0.f;
  for (int k = (t + 1) * 128; k < Sn; ++k) acc += bf2f(Vb[(size_t)k * HDn + n]);
  suffV[((size_t)bh * 16 + t) * 64 + n] = acc;
}

// Fused masked-QK^T -> (scale, causal mask to -1e9) -> @V, no softmax.
// 64 q-rows per block; k-tiles of 128 up to the diagonal; fully-masked
// remainder folded in analytically as -1e9 * suffix-sum(V).
__global__ __launch_bounds__(256)
void attn_kernel(const ushort_t* __restrict__ Q, const ushort_t* __restrict__ K,
                 const ushort_t* __restrict__ V, const float* __restrict__ suffV,
                 ushort_t* __restrict__ O) {
  __shared__ __align__(16) ushort_t Qs[64][72];
  __shared__ __align__(16) ushort_t Ks[128][72];
  __shared__ __align__(16) ushort_t Vts[64][136];  // V transposed: [hd][k]
  __shared__ __align__(16) ushort_t Ss[64][136];   // scores bf16 (C->A layout hop)

  const int tid = threadIdx.x, lane = tid & 63, w = tid >> 6;
  const int quad = lane >> 4, l16 = lane & 15;
  const int bh = blockIdx.y;
  const int q0 = blockIdx.x * 64;
  const int b = bh >> 4, h = bh & 15;
  const ushort_t* Qb = Q + (size_t)bh * Sn * HDn;
  const ushort_t* Kb = K + (size_t)bh * Sn * HDn;
  const ushort_t* Vb = V + (size_t)bh * Sn * HDn;

#pragma unroll
  for (int i = 0; i < 2; ++i) {            // stage Q tile 64x64 once
    int c = tid + i * 256;
    int r = c >> 3, cc = (c & 7) * 8;
    *(uint4*)(&Qs[r][cc]) = *(const uint4*)(Qb + (size_t)(q0 + r) * HDn + cc);
  }

  f32x4 oacc[4] = {};                       // 16 rows x 64 cols per wave
  const int tdiag = q0 >> 7;

  for (int t = 0; t <= tdiag; ++t) {
    __syncthreads();                        // prev iter's LDS reads done
#pragma unroll
    for (int i = 0; i < 4; ++i) {          // stage K tile 128x64
      int c = tid + i * 256;
      int r = c >> 3, cc = (c & 7) * 8;
      *(uint4*)(&Ks[r][cc]) = *(const uint4*)(Kb + (size_t)(t * 128 + r) * HDn + cc);
    }
#pragma unroll
    for (int i = 0; i < 4; ++i) {          // stage V tile transposed
      int c = tid + i * 256;
      int k = c >> 3, n0 = (c & 7) * 8;
      uint4 vv = *(const uint4*)(Vb + (size_t)(t * 128 + k) * HDn + n0);
      const ushort_t* pv = (const ushort_t*)&vv;
#pragma unroll
      for (int j = 0; j < 8; ++j) Vts[n0 + j][k] = pv[j];
    }
    __syncthreads();

    // scores: wave w computes rows [w*16, w*16+16) x 128 cols, K-dim 64
    f32x4 sacc[8] = {};
#pragma unroll
    for (int ks = 0; ks < 2; ++ks) {
      bf16x8 aq = *(const bf16x8*)(&Qs[w * 16 + l16][ks * 32 + quad * 8]);
#pragma unroll
      for (int nt = 0; nt < 8; ++nt) {
        bf16x8 bk8 = *(const bf16x8*)(&Ks[nt * 16 + l16][ks * 32 + quad * 8]);
        sacc[nt] = MFMA16(aq, bk8, sacc[nt]);
      }
    }
    // scale + causal mask -> Ss (own rows only: intra-wave LDS RAW is in-order)
#pragma unroll
    for (int nt = 0; nt < 8; ++nt) {
      int kk = nt * 16 + l16;
      int gk = t * 128 + kk;
#pragma unroll
      for (int r = 0; r < 4; ++r) {
        int rr = w * 16 + quad * 4 + r;
        float val = (gk > q0 + rr) ? NEG : sacc[nt][r] * SCALE;
        Ss[rr][kk] = f2bf(val);
      }
    }
    // PV: O += Ss(16x128) @ V(128x64)
#pragma unroll
    for (int ks = 0; ks < 4; ++ks) {
      bf16x8 as8 = *(const bf16x8*)(&Ss[w * 16 + l16][ks * 32 + quad * 8]);
#pragma unroll
      for (int nt = 0; nt < 4; ++nt) {
        bf16x8 bv8 = *(const bf16x8*)(&Vts[nt * 16 + l16][ks * 32 + quad * 8]);
        oacc[nt] = MFMA16(as8, bv8, oacc[nt]);
      }
    }
  }

  // fully-masked tail: O[q] += -1e9 * sum_{k >= (tdiag+1)*128} V[k]   (f32-exact)
  const float* sv = suffV + ((size_t)bh * 16 + tdiag) * 64;
#pragma unroll
  for (int nt = 0; nt < 4; ++nt) {
    float sfx = NEG * sv[nt * 16 + l16];
#pragma unroll
    for (int r = 0; r < 4; ++r) oacc[nt][r] += sfx;
  }

  // store O in [B,S,D] layout (d = h*64 + hd) for the final NT projection
#pragma unroll
  for (int nt = 0; nt < 4; ++nt) {
#pragma unroll
    for (int r = 0; r < 4; ++r) {
      int rr = w * 16 + quad * 4 + r;
      int s = q0 + rr;
      int n = nt * 16 + l16;
      O[(size_t)(b * Sn + s) * Dn + h * 64 + n] = f2bf(oacc[nt][r]);
    }
  }
}

extern "C" void kernel_launch(void* const* d_in, const int* in_sizes, int n_in,
                              void* d_out, int out_size, void* d_ws, size_t ws_size,
                              hipStream_t stream) {
  const float* Xq = (const float*)d_in[0];
  const float* Xk = (const float*)d_in[1];
  const float* Xv = (const float*)d_in[2];
  // d_in[3]: causal mask (int32) — tril, handled analytically
  const float* Wq = (const float*)d_in[4];
  const float* bq = (const float*)d_in[5];
  const float* Wk = (const float*)d_in[6];
  const float* bk = (const float*)d_in[7];
  const float* Wv = (const float*)d_in[8];
  const float* bv = (const float*)d_in[9];
  const float* Wo = (const float*)d_in[10];
  const float* bo = (const float*)d_in[11];

  // ws layout (bytes): Q 16MB | K 16MB | V 16MB | O 16MB | suffV 256KB (~64.3MB)
  char* ws = (char*)d_ws;
  ushort_t* Q  = (ushort_t*)(ws);
  ushort_t* Kh = (ushort_t*)(ws + (size_t)16777216);
  ushort_t* Vh = (ushort_t*)(ws + (size_t)33554432);
  ushort_t* Oh = (ushort_t*)(ws + (size_t)50331648);
  float*    sV = (float*)   (ws + (size_t)67108864);

  dim3 gg(8, 64), bb(256);
  gemm_bt<false, false><<<gg, bb, 0, stream>>>(Xq, Wq, bq, Q);
  gemm_bt<false, false><<<gg, bb, 0, stream>>>(Xk, Wk, bk, Kh);
  gemm_bt<false, false><<<gg, bb, 0, stream>>>(Xv, Wv, bv, Vh);
  suffv_kernel<<<dim3(64, 16), 64, 0, stream>>>(Vh, sV);
  attn_kernel<<<dim3(32, 64), 256, 0, stream>>>(Q, Kh, Vh, sV, Oh);
  gemm_bt<true, true><<<gg, bb, 0, stream>>>(Oh, Wo, bo, (float*)d_out);
}

// Round 3
// 412.917 us; speedup vs baseline: 1.8914x; 1.8914x over previous
//
#include <hip/hip_runtime.h>
#include <stdint.h>

typedef unsigned short ushort_t;
typedef __bf16 bf16x8 __attribute__((ext_vector_type(8)));
typedef float f32x4 __attribute__((ext_vector_type(4)));
typedef ushort_t us4 __attribute__((ext_vector_type(4)));

#define MFMA16(a, b, c) __builtin_amdgcn_mfma_f32_16x16x32_bf16((a), (b), (c), 0, 0, 0)

constexpr int Bn = 4, Sn = 2048, Dn = 1024, Hn = 16, HDn = 64;
constexpr float SCALE = 0.125f;   // 1/sqrt(64)
constexpr float NEG = -1e9f;

__device__ __forceinline__ float bf2f(ushort_t u) {
  unsigned x = ((unsigned)u) << 16;
  return __builtin_bit_cast(float, x);
}
__device__ __forceinline__ ushort_t f2bf(float f) {
  unsigned x = __builtin_bit_cast(unsigned, f);
  x = x + 0x7FFFu + ((x >> 16) & 1u);   // RNE
  return (ushort_t)(x >> 16);
}
__device__ __forceinline__ uint4 ld8_f32_bf16(const float* __restrict__ p) {
  float4 a = *(const float4*)p;
  float4 b = *(const float4*)(p + 4);
  union { ushort_t u[8]; uint4 v; } r;
  r.u[0] = f2bf(a.x); r.u[1] = f2bf(a.y); r.u[2] = f2bf(a.z); r.u[3] = f2bf(a.w);
  r.u[4] = f2bf(b.x); r.u[5] = f2bf(b.y); r.u[6] = f2bf(b.z); r.u[7] = f2bf(b.w);
  return r.v;
}
// async global->LDS, 16B per lane; LDS dest = wave-uniform base + lane*16
__device__ __forceinline__ void gl2lds16(const void* g, void* l) {
  __builtin_amdgcn_global_load_lds(
      (__attribute__((address_space(1))) void*)g,
      (__attribute__((address_space(3))) void*)l, 16, 0, 0);
}

// f32 -> bf16 elementwise; grid*256*8 elems
__global__ __launch_bounds__(256)
void cvt1(const float* __restrict__ s, ushort_t* __restrict__ d) {
  size_t i = ((size_t)blockIdx.x * 256 + threadIdx.x) * 8;
  *(uint4*)(d + i) = ld8_f32_bf16(s + i);
}

// C = A[M,K]bf16 @ W[N,K]bf16^T + bias(f32) via MFMA 16x16x32, m97-style
// global_load_lds staging with XOR-swizzled granules.
// EPI 0: scatter [B,H,S,HD] b16 (Q,K) | 1: scatter transposed [B,H,HD,S] b64 (Vt)
// EPI 2: f32 row-major [M,N] (final proj)
template <int EPI>
__global__ __launch_bounds__(256)
void gemm_bt(const ushort_t* __restrict__ A, const ushort_t* __restrict__ Wt,
             const float* __restrict__ bias, void* __restrict__ Cp) {
  constexpr int K = 1024;
  __shared__ __align__(16) ushort_t As[128 * 64];
  __shared__ __align__(16) ushort_t Bs[128 * 64];

  const int tid = threadIdx.x;
  const int lane = tid & 63, w = tid >> 6;
  const int quad = lane >> 4, l16 = lane & 15;
  const int wm = w >> 1, wn = w & 1;
  const int row0 = blockIdx.y * 128;
  const int col0 = blockIdx.x * 128;

  // staging: chunk c = w*4+i covers rows c*8..c*8+8 (64 elem = 128B rows)
  const int sr = lane >> 3;                      // row within chunk
  const int sg = ((lane & 7) ^ (sr & 7)) * 8;    // swizzled src granule
  const ushort_t* Ab = A  + (size_t)(row0 + w * 32 + sr) * K + sg;
  const ushort_t* Bb = Wt + (size_t)(col0 + w * 32 + sr) * K + sg;

  f32x4 acc[4][4] = {};

  for (int k0 = 0; k0 < K; k0 += 64) {
    __syncthreads();
#pragma unroll
    for (int i = 0; i < 4; ++i) {
      gl2lds16(Ab + (size_t)(i * 8) * K + k0, &As[(w * 32 + i * 8) * 64]);
      gl2lds16(Bb + (size_t)(i * 8) * K + k0, &Bs[(w * 32 + i * 8) * 64]);
    }
    __syncthreads();
#pragma unroll
    for (int ks = 0; ks < 2; ++ks) {
      const int kg = ((ks * 4 + quad) ^ (l16 & 7)) * 8;   // swizzled read granule
      bf16x8 af[4], bfr[4];
#pragma unroll
      for (int mt = 0; mt < 4; ++mt)
        af[mt] = *(const bf16x8*)(&As[(wm * 64 + mt * 16 + l16) * 64 + kg]);
#pragma unroll
      for (int nt = 0; nt < 4; ++nt)
        bfr[nt] = *(const bf16x8*)(&Bs[(wn * 64 + nt * 16 + l16) * 64 + kg]);
#pragma unroll
      for (int mt = 0; mt < 4; ++mt)
#pragma unroll
        for (int nt = 0; nt < 4; ++nt)
          acc[mt][nt] = MFMA16(af[mt], bfr[nt], acc[mt][nt]);
    }
  }

  // epilogue: C/D layout col=lane&15, row=quad*4+reg
#pragma unroll
  for (int mt = 0; mt < 4; ++mt) {
#pragma unroll
    for (int nt = 0; nt < 4; ++nt) {
      const int col = col0 + wn * 64 + nt * 16 + l16;
      const float bv = bias[col];
      const int rowb = row0 + wm * 64 + mt * 16 + quad * 4;
      if (EPI == 1) {        // Vt scatter: [b,h,hd,s], 4 consecutive s -> b64
        const int b = rowb >> 11, s = rowb & (Sn - 1);
        const int h = col >> 6, hd = col & 63;
        us4 pk;
#pragma unroll
        for (int r = 0; r < 4; ++r) pk[r] = f2bf(acc[mt][nt][r] + bv);
        *(us4*)((ushort_t*)Cp + ((size_t)((b * Hn + h) * HDn + hd)) * Sn + s) = pk;
      } else {
#pragma unroll
        for (int r = 0; r < 4; ++r) {
          const int row = rowb + r;
          const float outv = acc[mt][nt][r] + bv;
          if (EPI == 2) {
            ((float*)Cp)[(size_t)row * 1024 + col] = outv;
          } else {           // Q/K scatter: [b,h,s,hd]
            const int b = row >> 11, s = row & (Sn - 1);
            const int h = col >> 6, hd = col & 63;
            ((ushort_t*)Cp)[(((size_t)(b * Hn + h) * Sn + s) << 6) + hd] = f2bf(outv);
          }
        }
      }
    }
  }
}

// tilesum[bh][t][n] = sum_{k in [t*128,(t+1)*128)} Vt[bh][n][k]
__global__ __launch_bounds__(64)
void tilesum_kernel(const ushort_t* __restrict__ Vt, float* __restrict__ tile) {
  const int bh = blockIdx.x, t = blockIdx.y, n = threadIdx.x;
  const ushort_t* p = Vt + ((size_t)bh * HDn + n) * Sn + t * 128;
  float acc = 0.f;
#pragma unroll
  for (int j = 0; j < 16; ++j) {
    union { uint4 v; ushort_t u[8]; } c;
    c.v = *(const uint4*)(p + j * 8);
#pragma unroll
    for (int e = 0; e < 8; ++e) acc += bf2f(c.u[e]);
  }
  tile[((size_t)bh * 16 + t) * 64 + n] = acc;
}

// suffV[bh][t][n] = sum_{t' > t} tilesum[bh][t'][n]
__global__ __launch_bounds__(64)
void suffix_kernel(const float* __restrict__ tile, float* __restrict__ suffV) {
  const int bh = blockIdx.x, n = threadIdx.x;
  float acc = 0.f;
  suffV[((size_t)bh * 16 + 15) * 64 + n] = 0.f;
  for (int t = 14; t >= 0; --t) {
    acc += tile[((size_t)bh * 16 + t + 1) * 64 + n];
    suffV[((size_t)bh * 16 + t) * 64 + n] = acc;
  }
}

// Fused masked-QK^T -> scale/mask -> @V (no softmax).
// Scores computed transposed (S^T = K·Q^T) so C-frag r-values are consecutive
// keys -> b64 Ss writes. PV computed as O^T = V^T·S^T (A from Vt, B from Ss,
// both contiguous-k b128 reads). Masked tail beyond diagonal folded in as
// -1e9 * suffix-sum(V).
__global__ __launch_bounds__(256)
void attn_kernel(const ushort_t* __restrict__ Q, const ushort_t* __restrict__ K,
                 const ushort_t* __restrict__ Vt, const float* __restrict__ suffV,
                 ushort_t* __restrict__ O) {
  __shared__ __align__(16) ushort_t Qs[64][72];     // padded, vector-staged once
  __shared__ __align__(16) ushort_t Ks[128 * 64];   // gl2lds, swizzled mod 8
  __shared__ __align__(16) ushort_t Vts[64 * 128];  // gl2lds, swizzled mod 16
  __shared__ __align__(16) ushort_t Ss[64][136];    // S^T hop, padded

  const int tid = threadIdx.x, lane = tid & 63, w = tid >> 6;
  const int quad = lane >> 4, l16 = lane & 15;
  const int bh = blockIdx.y;
  const int qt = 31 - blockIdx.x;          // heavy (diagonal) blocks first
  const int q0 = qt * 64;
  const int b = bh >> 4, h = bh & 15;
  const ushort_t* Qb = Q + (size_t)bh * Sn * HDn;
  const ushort_t* Kb = K + (size_t)bh * Sn * HDn;
  const ushort_t* Vtb = Vt + (size_t)bh * HDn * Sn;

#pragma unroll
  for (int i = 0; i < 2; ++i) {            // stage Q tile 64x64 (bf16, padded)
    int c = tid + i * 256;
    int r = c >> 3, cc = (c & 7) * 8;
    *(uint4*)(&Qs[r][cc]) = *(const uint4*)(Qb + (size_t)(q0 + r) * HDn + cc);
  }

  // K staging per-lane consts (chunk c=w*4+i: rows c*8.., 128B rows)
  const int kr = lane >> 3;
  const int kg = ((lane & 7) ^ (kr & 7)) * 8;

  f32x4 oacc[4] = {};                       // O^T: 64 n-rows x 16 q-cols per wave
  const int tdiag = q0 >> 7;

  for (int t = 0; t <= tdiag; ++t) {
    __syncthreads();
#pragma unroll
    for (int i = 0; i < 4; ++i)            // K tile 128x64
      gl2lds16(Kb + (size_t)(t * 128 + w * 32 + i * 8 + kr) * HDn + kg,
               &Ks[(w * 32 + i * 8) * 64]);
#pragma unroll
    for (int i = 0; i < 4; ++i) {          // Vt tile 64x128 (256B rows)
      int n = w * 16 + i * 4 + (lane >> 4);
      int sg2 = ((lane & 15) ^ (n & 15)) * 8;
      gl2lds16(Vtb + (size_t)n * Sn + t * 128 + sg2, &Vts[(w * 16 + i * 4) * 128]);
    }
    __syncthreads();

    // S^T tiles: A = K rows (keys), B = Q^T; D col=q(l16), row=key(quad*4+r)
    f32x4 sacc[8] = {};
#pragma unroll
    for (int ks = 0; ks < 2; ++ks) {
      bf16x8 bq = *(const bf16x8*)(&Qs[w * 16 + l16][ks * 32 + quad * 8]);
      const int rg = ((ks * 4 + quad) ^ (l16 & 7)) * 8;
#pragma unroll
      for (int nt = 0; nt < 8; ++nt) {
        bf16x8 ak = *(const bf16x8*)(&Ks[(nt * 16 + l16) * 64 + rg]);
        sacc[nt] = MFMA16(ak, bq, sacc[nt]);
      }
    }
    // scale + causal mask -> Ss[q_local][key_local] via packed b64 writes
    const int q = q0 + w * 16 + l16;
#pragma unroll
    for (int nt = 0; nt < 8; ++nt) {
      const int kbase = t * 128 + nt * 16 + quad * 4;
      us4 pk;
#pragma unroll
      for (int r = 0; r < 4; ++r) {
        float val = (kbase + r > q) ? NEG : sacc[nt][r] * SCALE;
        pk[r] = f2bf(val);
      }
      *(us4*)(&Ss[w * 16 + l16][nt * 16 + quad * 4]) = pk;
    }
    // O^T += V^T · S^T  (intra-wave LDS RAW on Ss rows, in-order DS pipe)
#pragma unroll
    for (int ks2 = 0; ks2 < 4; ++ks2) {
      bf16x8 bs8 = *(const bf16x8*)(&Ss[w * 16 + l16][ks2 * 32 + quad * 8]);
#pragma unroll
      for (int nt2 = 0; nt2 < 4; ++nt2) {
        bf16x8 av = *(const bf16x8*)(
            &Vts[(nt2 * 16 + l16) * 128 + (((ks2 * 4 + quad) ^ l16) * 8)]);
        oacc[nt2] = MFMA16(av, bs8, oacc[nt2]);
      }
    }
  }

  // masked tail + store: lane holds q fixed (l16), n = nt2*16+quad*4+r -> b64
  const float* sv = suffV + ((size_t)bh * 16 + tdiag) * 64;
  const int s = q0 + w * 16 + l16;
#pragma unroll
  for (int nt2 = 0; nt2 < 4; ++nt2) {
    const int nb = nt2 * 16 + quad * 4;
    us4 pk;
#pragma unroll
    for (int r = 0; r < 4; ++r) pk[r] = f2bf(oacc[nt2][r] + NEG * sv[nb + r]);
    *(us4*)(&O[((size_t)(b * Sn + s)) * Dn + h * 64 + nb]) = pk;
  }
}

extern "C" void kernel_launch(void* const* d_in, const int* in_sizes, int n_in,
                              void* d_out, int out_size, void* d_ws, size_t ws_size,
                              hipStream_t stream) {
  const float* Xq = (const float*)d_in[0];
  const float* Xk = (const float*)d_in[1];
  const float* Xv = (const float*)d_in[2];
  // d_in[3]: causal mask (int32) — tril, handled analytically
  const float* Wq = (const float*)d_in[4];
  const float* bq = (const float*)d_in[5];
  const float* Wk = (const float*)d_in[6];
  const float* bk = (const float*)d_in[7];
  const float* Wv = (const float*)d_in[8];
  const float* bv = (const float*)d_in[9];
  const float* Wo = (const float*)d_in[10];
  const float* bo = (const float*)d_in[11];

  // ws: bufA(X-cvt, later attn-O) 16MB | Q 16MB | K 16MB | Vt 16MB | Wb 2MB |
  //     tilesum 256KB | suffV 256KB   => 66.5MB total
  char* ws = (char*)d_ws;
  ushort_t* bufA = (ushort_t*)(ws);
  ushort_t* Qb   = (ushort_t*)(ws + (size_t)16 * 1024 * 1024);
  ushort_t* Kb   = (ushort_t*)(ws + (size_t)32 * 1024 * 1024);
  ushort_t* Vtb  = (ushort_t*)(ws + (size_t)48 * 1024 * 1024);
  ushort_t* Wb   = (ushort_t*)(ws + (size_t)64 * 1024 * 1024);
  float*    tsum = (float*)   (ws + (size_t)66 * 1024 * 1024);
  float*    sV   = (float*)   (ws + (size_t)66 * 1024 * 1024 + 262144);

  const dim3 gg(8, 64), bb(256);
  cvt1<<<512, 256, 0, stream>>>(Wq, Wb);
  cvt1<<<4096, 256, 0, stream>>>(Xq, bufA);
  gemm_bt<0><<<gg, bb, 0, stream>>>(bufA, Wb, bq, Qb);
  cvt1<<<512, 256, 0, stream>>>(Wk, Wb);
  cvt1<<<4096, 256, 0, stream>>>(Xk, bufA);
  gemm_bt<0><<<gg, bb, 0, stream>>>(bufA, Wb, bk, Kb);
  cvt1<<<512, 256, 0, stream>>>(Wv, Wb);
  cvt1<<<4096, 256, 0, stream>>>(Xv, bufA);
  gemm_bt<1><<<gg, bb, 0, stream>>>(bufA, Wb, bv, Vtb);
  tilesum_kernel<<<dim3(64, 16), 64, 0, stream>>>(Vtb, tsum);
  suffix_kernel<<<64, 64, 0, stream>>>(tsum, sV);
  attn_kernel<<<dim3(32, 64), 256, 0, stream>>>(Qb, Kb, Vtb, sV, bufA);
  cvt1<<<512, 256, 0, stream>>>(Wo, Wb);
  gemm_bt<2><<<gg, bb, 0, stream>>>(bufA, Wb, bo, (float*)d_out);
}

// Round 4
// 348.501 us; speedup vs baseline: 2.2410x; 1.1848x over previous
//
#include <hip/hip_runtime.h>
#include <stdint.h>

typedef unsigned short ushort_t;
typedef __bf16 bf16x8 __attribute__((ext_vector_type(8)));
typedef float f32x4 __attribute__((ext_vector_type(4)));
typedef ushort_t us4 __attribute__((ext_vector_type(4)));

#define MFMA16(a, b, c) __builtin_amdgcn_mfma_f32_16x16x32_bf16((a), (b), (c), 0, 0, 0)

constexpr int Bn = 4, Sn = 2048, Dn = 1024, Hn = 16, HDn = 64;
constexpr float SCALE = 0.125f;   // 1/sqrt(64)
constexpr float NEG = -1e9f;

__device__ __forceinline__ float bf2f(ushort_t u) {
  unsigned x = ((unsigned)u) << 16;
  return __builtin_bit_cast(float, x);
}
__device__ __forceinline__ ushort_t f2bf(float f) {
  unsigned x = __builtin_bit_cast(unsigned, f);
  x = x + 0x7FFFu + ((x >> 16) & 1u);   // RNE
  return (ushort_t)(x >> 16);
}
__device__ __forceinline__ uint4 ld8_f32_bf16(const float* __restrict__ p) {
  float4 a = *(const float4*)p;
  float4 b = *(const float4*)(p + 4);
  union { ushort_t u[8]; uint4 v; } r;
  r.u[0] = f2bf(a.x); r.u[1] = f2bf(a.y); r.u[2] = f2bf(a.z); r.u[3] = f2bf(a.w);
  r.u[4] = f2bf(b.x); r.u[5] = f2bf(b.y); r.u[6] = f2bf(b.z); r.u[7] = f2bf(b.w);
  return r.v;
}
// async global->LDS, 16B per lane; LDS dest = wave-uniform base + lane*16
__device__ __forceinline__ void gl2lds16(const void* g, void* l) {
  __builtin_amdgcn_global_load_lds(
      (__attribute__((address_space(1))) void*)g,
      (__attribute__((address_space(3))) void*)l, 16, 0, 0);
}

// fused W (first 512 blocks) + X (next 4096 blocks) f32->bf16 conversion
__global__ __launch_bounds__(256)
void cvt2(const float* __restrict__ X, ushort_t* __restrict__ Xd,
          const float* __restrict__ W, ushort_t* __restrict__ Wd) {
  int bid = blockIdx.x;
  if (bid < 512) {
    size_t i = ((size_t)bid * 256 + threadIdx.x) * 8;
    *(uint4*)(Wd + i) = ld8_f32_bf16(W + i);
  } else {
    size_t i = ((size_t)(bid - 512) * 256 + threadIdx.x) * 8;
    *(uint4*)(Xd + i) = ld8_f32_bf16(X + i);
  }
}
__global__ __launch_bounds__(256)
void cvt1(const float* __restrict__ s, ushort_t* __restrict__ d) {
  size_t i = ((size_t)blockIdx.x * 256 + threadIdx.x) * 8;
  *(uint4*)(d + i) = ld8_f32_bf16(s + i);
}

// C = A[M,K]bf16 @ W[N,K]bf16^T + bias(f32), MFMA 16x16x32, gl2lds staging
// with XOR-swizzled granules (validated R3).
// EPI 0: scatter [B,H,S,HD] b16 (Q) | 1: transposed [B,H,HD,S] b64 (Kt,Vt)
// EPI 2: f32 row-major [M,N] (final proj -> d_out)
template <int EPI>
__global__ __launch_bounds__(256)
void gemm_bt(const ushort_t* __restrict__ A, const ushort_t* __restrict__ Wt,
             const float* __restrict__ bias, void* __restrict__ Cp) {
  constexpr int K = 1024;
  __shared__ __align__(16) ushort_t As[128 * 64];
  __shared__ __align__(16) ushort_t Bs[128 * 64];

  const int tid = threadIdx.x;
  const int lane = tid & 63, w = tid >> 6;
  const int quad = lane >> 4, l16 = lane & 15;
  const int wm = w >> 1, wn = w & 1;
  const int row0 = blockIdx.y * 128;
  const int col0 = blockIdx.x * 128;

  const int sr = lane >> 3;
  const int sg = ((lane & 7) ^ (sr & 7)) * 8;
  const ushort_t* Ab = A  + (size_t)(row0 + w * 32 + sr) * K + sg;
  const ushort_t* Bb = Wt + (size_t)(col0 + w * 32 + sr) * K + sg;

  f32x4 acc[4][4] = {};

  for (int k0 = 0; k0 < K; k0 += 64) {
    __syncthreads();
#pragma unroll
    for (int i = 0; i < 4; ++i) {
      gl2lds16(Ab + (size_t)(i * 8) * K + k0, &As[(w * 32 + i * 8) * 64]);
      gl2lds16(Bb + (size_t)(i * 8) * K + k0, &Bs[(w * 32 + i * 8) * 64]);
    }
    __syncthreads();
#pragma unroll
    for (int ks = 0; ks < 2; ++ks) {
      const int kg = ((ks * 4 + quad) ^ (l16 & 7)) * 8;
      bf16x8 af[4], bfr[4];
#pragma unroll
      for (int mt = 0; mt < 4; ++mt)
        af[mt] = *(const bf16x8*)(&As[(wm * 64 + mt * 16 + l16) * 64 + kg]);
#pragma unroll
      for (int nt = 0; nt < 4; ++nt)
        bfr[nt] = *(const bf16x8*)(&Bs[(wn * 64 + nt * 16 + l16) * 64 + kg]);
#pragma unroll
      for (int mt = 0; mt < 4; ++mt)
#pragma unroll
        for (int nt = 0; nt < 4; ++nt)
          acc[mt][nt] = MFMA16(af[mt], bfr[nt], acc[mt][nt]);
    }
  }

#pragma unroll
  for (int mt = 0; mt < 4; ++mt) {
#pragma unroll
    for (int nt = 0; nt < 4; ++nt) {
      const int col = col0 + wn * 64 + nt * 16 + l16;
      const float bv = bias[col];
      const int rowb = row0 + wm * 64 + mt * 16 + quad * 4;
      if (EPI == 1) {        // transposed scatter: [b,h,hd,s], b64 over s
        const int b = rowb >> 11, s = rowb & (Sn - 1);
        const int h = col >> 6, hd = col & 63;
        us4 pk;
#pragma unroll
        for (int r = 0; r < 4; ++r) pk[r] = f2bf(acc[mt][nt][r] + bv);
        *(us4*)((ushort_t*)Cp + ((size_t)((b * Hn + h) * HDn + hd)) * Sn + s) = pk;
      } else {
#pragma unroll
        for (int r = 0; r < 4; ++r) {
          const int row = rowb + r;
          const float outv = acc[mt][nt][r] + bv;
          if (EPI == 2) {
            ((float*)Cp)[(size_t)row * 1024 + col] = outv;
          } else {           // Q scatter: [b,h,s,hd]
            const int b = row >> 11, s = row & (Sn - 1);
            const int h = col >> 6, hd = col & 63;
            ((ushort_t*)Cp)[(((size_t)(b * Hn + h) * Sn + s) << 6) + hd] = f2bf(outv);
          }
        }
      }
    }
  }
}

// tsum[bh][t][n] = sum_{k in [t*64,(t+1)*64)} Vt[bh][n][k]
__global__ __launch_bounds__(64)
void tilesum64(const ushort_t* __restrict__ Vt, float* __restrict__ tsum) {
  const int bh = blockIdx.x, t = blockIdx.y, n = threadIdx.x;
  const ushort_t* p = Vt + ((size_t)bh * HDn + n) * Sn + t * 64;
  float acc = 0.f;
#pragma unroll
  for (int j = 0; j < 8; ++j) {
    union { uint4 v; ushort_t u[8]; } c;
    c.v = *(const uint4*)(p + j * 8);
#pragma unroll
    for (int e = 0; e < 8; ++e) acc += bf2f(c.u[e]);
  }
  tsum[((size_t)bh * 32 + t) * 64 + n] = acc;
}

// suffV[bh][t][n] = sum_{t' > t} tsum[bh][t'][n]
__global__ __launch_bounds__(64)
void suffix64(const float* __restrict__ tsum, float* __restrict__ suffV) {
  const int bh = blockIdx.x, n = threadIdx.x;
  float acc = 0.f;
  suffV[((size_t)bh * 32 + 31) * 64 + n] = 0.f;
  for (int t = 30; t >= 0; --t) {
    acc += tsum[((size_t)bh * 32 + t + 1) * 64 + n];
    suffV[((size_t)bh * 32 + t) * 64 + n] = acc;
  }
}

// Prefix kernel: Z'_qt[n_v][d_k] = (1/8)*sum_{k < qt*64} K[k][d_k]*V[k][n_v]
// (bf16, one 64x64 matrix per (bh,qt)). G_t = K_t^T V_t via MFMA: A = Kt rows,
// B = Vt rows, contraction over s. Prefix accumulated in fp32 regs.
__global__ __launch_bounds__(256)
void prefixz(const ushort_t* __restrict__ Kt, const ushort_t* __restrict__ Vt,
             ushort_t* __restrict__ Zp) {
  __shared__ __align__(16) ushort_t Kts[64 * 64];
  __shared__ __align__(16) ushort_t Vts[64 * 64];
  const int tid = threadIdx.x, lane = tid & 63, w = tid >> 6;
  const int quad = lane >> 4, l16 = lane & 15;
  const int bh = blockIdx.x;
  const ushort_t* Ktb = Kt + (size_t)bh * HDn * Sn;
  const ushort_t* Vtb = Vt + (size_t)bh * HDn * Sn;

  const int sr = lane >> 3;                     // row-in-chunk (hd)
  const int sg = ((lane & 7) ^ (sr & 7)) * 8;   // swizzled src granule

  f32x4 zacc[4] = {};   // wave w: d_k rows w*16+quad*4+r, n_v cols nt*16+l16

  for (int t = 0; t < 32; ++t) {
    __syncthreads();
#pragma unroll
    for (int c = 0; c < 2; ++c) {
      const int row = w * 16 + c * 8;
      gl2lds16(Ktb + (size_t)(row + sr) * Sn + t * 64 + sg, &Kts[row * 64]);
      gl2lds16(Vtb + (size_t)(row + sr) * Sn + t * 64 + sg, &Vts[row * 64]);
    }
    __syncthreads();
    // store prefix (= sum over t' < t) for this qt=t, then accumulate G_t
    ushort_t* zd = Zp + (size_t)(bh * 32 + t) * 4096;
#pragma unroll
    for (int nt = 0; nt < 4; ++nt) {
      us4 pk;
#pragma unroll
      for (int r = 0; r < 4; ++r) pk[r] = f2bf(SCALE * zacc[nt][r]);
      *(us4*)(zd + (nt * 16 + l16) * 64 + w * 16 + quad * 4) = pk;
    }
    if (t < 31) {
#pragma unroll
      for (int ks = 0; ks < 2; ++ks) {
        const int kg = ((ks * 4 + quad) ^ (l16 & 7)) * 8;
        bf16x8 ak = *(const bf16x8*)(&Kts[(w * 16 + l16) * 64 + kg]);
#pragma unroll
        for (int nt = 0; nt < 4; ++nt) {
          bf16x8 bv = *(const bf16x8*)(&Vts[(nt * 16 + l16) * 64 + kg]);
          zacc[nt] = MFMA16(ak, bv, zacc[nt]);
        }
      }
    }
  }
}

// One-shot attention block (64 q-rows): O^T = Z'·Q^T + V_d^T·S_d^T + tail.
// Z' covers all keys < q0 (prefix); diagonal 64-key tile masked explicitly;
// keys >= q0+64 contribute -1e9 * suffV.
__global__ __launch_bounds__(256)
void attn_kernel(const ushort_t* __restrict__ Q, const ushort_t* __restrict__ Kt,
                 const ushort_t* __restrict__ Vt, const ushort_t* __restrict__ Zp,
                 const float* __restrict__ suffV, ushort_t* __restrict__ O) {
  __shared__ __align__(16) ushort_t Qs[64 * 64];    // gl2lds, swizzled
  __shared__ __align__(16) ushort_t Vts[64 * 64];   // gl2lds, swizzled
  __shared__ __align__(16) ushort_t Zs[64 * 64];    // gl2lds, swizzled
  __shared__ __align__(16) ushort_t Ks[64 * 64];    // Kt transposed in-kernel, swizzled
  __shared__ __align__(16) ushort_t Ss[64][72];     // S^T->S hop, padded

  const int tid = threadIdx.x, lane = tid & 63, w = tid >> 6;
  const int quad = lane >> 4, l16 = lane & 15;
  const int bh = blockIdx.y;
  const int qt = blockIdx.x;
  const int q0 = qt * 64;
  const int b = bh >> 4, h = bh & 15;
  const ushort_t* Qb  = Q  + (size_t)bh * Sn * HDn;
  const ushort_t* Ktb = Kt + (size_t)bh * HDn * Sn;
  const ushort_t* Vtb = Vt + (size_t)bh * HDn * Sn;
  const ushort_t* Zb  = Zp + (size_t)(bh * 32 + qt) * 4096;

  const int sr = lane >> 3;
  const int sg = ((lane & 7) ^ (sr & 7)) * 8;

  // ---- staging ----
#pragma unroll
  for (int c = 0; c < 2; ++c) {
    const int row = w * 16 + c * 8;
    gl2lds16(Qb + (size_t)(q0 + row + sr) * HDn + sg, &Qs[row * 64]);
    gl2lds16(Vtb + (size_t)(row + sr) * Sn + q0 + sg, &Vts[row * 64]);
    gl2lds16(Zb + (size_t)(row + sr) * 64 + sg, &Zs[row * 64]);
  }
  // Kt diagonal tile -> transpose to Ks[s][hd] (swizzled granules, rotated
  // element order for bank spread)
  const int q8 = lane & 7, h8 = lane >> 3;
#pragma unroll
  for (int c = 0; c < 2; ++c) {
    const int hd = w * 16 + c * 8 + h8;
    const int G = hd >> 3;
    union { uint4 v; ushort_t u[8]; } kv;
    kv.v = *(const uint4*)(Ktb + (size_t)hd * Sn + q0 + q8 * 8);
#pragma unroll
    for (int j = 0; j < 8; ++j) {
      const int e = (j + q8) & 7;            // rotate: concurrent s-rows differ
      const int s = q8 * 8 + e;
      Ks[s * 64 + ((G ^ e) << 3) + (hd & 7)] = kv.u[e];
    }
  }
  __syncthreads();

  // ---- compute (one shot) ----
  bf16x8 bq[2];
#pragma unroll
  for (int ks = 0; ks < 2; ++ks)
    bq[ks] = *(const bf16x8*)(&Qs[(w * 16 + l16) * 64 + (((ks * 4 + quad) ^ (l16 & 7)) << 3)]);

  f32x4 oacc[4] = {};   // O^T: rows n_v = nt*16+quad*4+r, col q = w*16+l16
  // prefix part: O^T += Z' · Q^T
#pragma unroll
  for (int ks = 0; ks < 2; ++ks) {
    const int kg = ((ks * 4 + quad) ^ (l16 & 7)) * 8;
#pragma unroll
    for (int nt = 0; nt < 4; ++nt) {
      bf16x8 az = *(const bf16x8*)(&Zs[(nt * 16 + l16) * 64 + kg]);
      oacc[nt] = MFMA16(az, bq[ks], oacc[nt]);
    }
  }
  // diagonal: S^T = K_d · Q^T (rows=key, cols=q)
  f32x4 sacc[4] = {};
#pragma unroll
  for (int ks = 0; ks < 2; ++ks) {
    const int kg = ((ks * 4 + quad) ^ (l16 & 7)) * 8;
#pragma unroll
    for (int nt = 0; nt < 4; ++nt) {
      bf16x8 ak = *(const bf16x8*)(&Ks[(nt * 16 + l16) * 64 + kg]);
      sacc[nt] = MFMA16(ak, bq[ks], sacc[nt]);
    }
  }
  // mask + scale -> Ss[q][key] (b64 packed; intra-wave rows only)
  const int qrel = w * 16 + l16;
#pragma unroll
  for (int nt = 0; nt < 4; ++nt) {
    const int kb = nt * 16 + quad * 4;
    us4 pk;
#pragma unroll
    for (int r = 0; r < 4; ++r) {
      float val = (kb + r > qrel) ? NEG : sacc[nt][r] * SCALE;
      pk[r] = f2bf(val);
    }
    *(us4*)(&Ss[qrel][kb]) = pk;
  }
  // PV: O^T += V_d^T · S_d^T  (intra-wave LDS RAW, DS pipe in-order)
#pragma unroll
  for (int ks = 0; ks < 2; ++ks) {
    bf16x8 bs = *(const bf16x8*)(&Ss[qrel][ks * 32 + quad * 8]);
#pragma unroll
    for (int nt = 0; nt < 4; ++nt) {
      bf16x8 av = *(const bf16x8*)(&Vts[(nt * 16 + l16) * 64 + (((ks * 4 + quad) ^ (l16 & 7)) << 3)]);
      oacc[nt] = MFMA16(av, bs, oacc[nt]);
    }
  }

  // masked tail + store O[b,s,d] (b64 over n)
  const float* sv = suffV + (size_t)(bh * 32 + qt) * 64;
  const int s = q0 + w * 16 + l16;
#pragma unroll
  for (int nt = 0; nt < 4; ++nt) {
    const int nb = nt * 16 + quad * 4;
    float4 s4 = *(const float4*)(sv + nb);
    us4 pk;
    pk[0] = f2bf(oacc[nt][0] + NEG * s4.x);
    pk[1] = f2bf(oacc[nt][1] + NEG * s4.y);
    pk[2] = f2bf(oacc[nt][2] + NEG * s4.z);
    pk[3] = f2bf(oacc[nt][3] + NEG * s4.w);
    *(us4*)(&O[((size_t)(b * Sn + s)) * Dn + h * 64 + nb]) = pk;
  }
}

extern "C" void kernel_launch(void* const* d_in, const int* in_sizes, int n_in,
                              void* d_out, int out_size, void* d_ws, size_t ws_size,
                              hipStream_t stream) {
  const float* Xq = (const float*)d_in[0];
  const float* Xk = (const float*)d_in[1];
  const float* Xv = (const float*)d_in[2];
  // d_in[3]: causal mask (int32) — tril, handled analytically
  const float* Wq = (const float*)d_in[4];
  const float* bq = (const float*)d_in[5];
  const float* Wk = (const float*)d_in[6];
  const float* bk = (const float*)d_in[7];
  const float* Wv = (const float*)d_in[8];
  const float* bv = (const float*)d_in[9];
  const float* Wo = (const float*)d_in[10];
  const float* bo = (const float*)d_in[11];

  // ws (MiB offsets): [0,16) Xb then Z (Xb dead after V-gemm) | [16,32) Q |
  // [32,48) Kt | [48,64) Vt | [64,80) O | [80,82) Wb | [82,82.5) tsum |
  // [82.5,83) suffV.  Total 83 MiB (R3 successfully used ~70 MB of ws).
  constexpr size_t MiB = 1024 * 1024;
  char* ws = (char*)d_ws;
  ushort_t* Xb  = (ushort_t*)(ws);
  ushort_t* Zp  = (ushort_t*)(ws);              // shares Xb (disjoint lifetime)
  ushort_t* Qb  = (ushort_t*)(ws + 16 * MiB);
  ushort_t* Ktb = (ushort_t*)(ws + 32 * MiB);
  ushort_t* Vtb = (ushort_t*)(ws + 48 * MiB);
  ushort_t* Ob  = (ushort_t*)(ws + 64 * MiB);
  ushort_t* Wb  = (ushort_t*)(ws + 80 * MiB);
  float*    ts  = (float*)   (ws + 82 * MiB);
  float*    sV  = (float*)   (ws + 82 * MiB + 512 * 1024);

  const dim3 gg(8, 64), bb(256);
  cvt2<<<4608, 256, 0, stream>>>(Xq, Xb, Wq, Wb);
  gemm_bt<0><<<gg, bb, 0, stream>>>(Xb, Wb, bq, Qb);
  cvt2<<<4608, 256, 0, stream>>>(Xk, Xb, Wk, Wb);
  gemm_bt<1><<<gg, bb, 0, stream>>>(Xb, Wb, bk, Ktb);
  cvt2<<<4608, 256, 0, stream>>>(Xv, Xb, Wv, Wb);
  gemm_bt<1><<<gg, bb, 0, stream>>>(Xb, Wb, bv, Vtb);
  tilesum64<<<dim3(64, 32), 64, 0, stream>>>(Vtb, ts);
  suffix64<<<64, 64, 0, stream>>>(ts, sV);
  prefixz<<<64, 256, 0, stream>>>(Ktb, Vtb, Zp);
  attn_kernel<<<dim3(32, 64), 256, 0, stream>>>(Qb, Ktb, Vtb, Zp, sV, Ob);
  cvt1<<<512, 256, 0, stream>>>(Wo, Wb);
  gemm_bt<2><<<gg, bb, 0, stream>>>(Ob, Wb, bo, (float*)d_out);
}

// Round 5
// 330.483 us; speedup vs baseline: 2.3632x; 1.0545x over previous
//
#include <hip/hip_runtime.h>
#include <stdint.h>

typedef unsigned short ushort_t;
typedef __bf16 bf16x8 __attribute__((ext_vector_type(8)));
typedef float f32x4 __attribute__((ext_vector_type(4)));
typedef ushort_t us4 __attribute__((ext_vector_type(4)));

#define MFMA16(a, b, c) __builtin_amdgcn_mfma_f32_16x16x32_bf16((a), (b), (c), 0, 0, 0)

constexpr int Bn = 4, Sn = 2048, Dn = 1024, Hn = 16, HDn = 64;
constexpr float SCALE = 0.125f;   // 1/sqrt(64)
constexpr float NEG = -1e9f;

__device__ __forceinline__ float bf2f(ushort_t u) {
  unsigned x = ((unsigned)u) << 16;
  return __builtin_bit_cast(float, x);
}
__device__ __forceinline__ ushort_t f2bf(float f) {
  unsigned x = __builtin_bit_cast(unsigned, f);
  x = x + 0x7FFFu + ((x >> 16) & 1u);   // RNE
  return (ushort_t)(x >> 16);
}
__device__ __forceinline__ uint4 ld8_f32_bf16(const float* __restrict__ p) {
  float4 a = *(const float4*)p;
  float4 b = *(const float4*)(p + 4);
  union { ushort_t u[8]; uint4 v; } r;
  r.u[0] = f2bf(a.x); r.u[1] = f2bf(a.y); r.u[2] = f2bf(a.z); r.u[3] = f2bf(a.w);
  r.u[4] = f2bf(b.x); r.u[5] = f2bf(b.y); r.u[6] = f2bf(b.z); r.u[7] = f2bf(b.w);
  return r.v;
}
// async global->LDS, 16B per lane; LDS dest = wave-uniform base + lane*16
__device__ __forceinline__ void gl2lds16(const void* g, void* l) {
  __builtin_amdgcn_global_load_lds(
      (__attribute__((address_space(1))) void*)g,
      (__attribute__((address_space(3))) void*)l, 16, 0, 0);
}

// One-shot conversion of all f32 inputs to bf16: 3 X (4096 blocks each) then
// 4 W (512 blocks each). Xd: 3x8388608 elems contiguous; Wd: 4x1048576.
__global__ __launch_bounds__(256)
void cvt_all(const float* __restrict__ xq, const float* __restrict__ xk,
             const float* __restrict__ xv, const float* __restrict__ wq,
             const float* __restrict__ wk, const float* __restrict__ wv,
             const float* __restrict__ wo, ushort_t* __restrict__ Xd,
             ushort_t* __restrict__ Wd) {
  const int bid = blockIdx.x;
  if (bid < 12288) {
    const int which = bid >> 12;
    const float* s = which == 0 ? xq : which == 1 ? xk : xv;
    size_t i = ((size_t)(bid & 4095) * 256 + threadIdx.x) * 8;
    *(uint4*)(Xd + (size_t)which * 8388608 + i) = ld8_f32_bf16(s + i);
  } else {
    const int wb = bid - 12288, which = wb >> 9;
    const float* s = which == 0 ? wq : which == 1 ? wk : which == 2 ? wv : wo;
    size_t i = ((size_t)(wb & 511) * 256 + threadIdx.x) * 8;
    *(uint4*)(Wd + (size_t)which * 1048576 + i) = ld8_f32_bf16(s + i);
  }
}

// Fused Q/K/V projections: z = 0/1/2 selects X, W, bias, dst, epilogue.
// z=0: Q scatter [B,H,S,HD] b16. z=1,2: transposed scatter [B,H,HD,S] b64.
__global__ __launch_bounds__(256)
void gemm_qkv(const ushort_t* __restrict__ Xb, const ushort_t* __restrict__ Wb,
              const float* __restrict__ bq, const float* __restrict__ bk,
              const float* __restrict__ bv, ushort_t* __restrict__ Qd,
              ushort_t* __restrict__ Ktd, ushort_t* __restrict__ Vtd) {
  constexpr int K = 1024;
  __shared__ __align__(16) ushort_t As[128 * 64];
  __shared__ __align__(16) ushort_t Bs[128 * 64];

  const int z = blockIdx.z;
  const ushort_t* A  = Xb + (size_t)z * 8388608;
  const ushort_t* Wt = Wb + (size_t)z * 1048576;
  const float* bias = z == 0 ? bq : z == 1 ? bk : bv;
  ushort_t* Cp = z == 0 ? Qd : z == 1 ? Ktd : Vtd;

  const int tid = threadIdx.x;
  const int lane = tid & 63, w = tid >> 6;
  const int quad = lane >> 4, l16 = lane & 15;
  const int wm = w >> 1, wn = w & 1;
  const int row0 = blockIdx.y * 128;
  const int col0 = blockIdx.x * 128;

  const int sr = lane >> 3;
  const int sg = ((lane & 7) ^ (sr & 7)) * 8;
  const ushort_t* Ab = A  + (size_t)(row0 + w * 32 + sr) * K + sg;
  const ushort_t* Bb = Wt + (size_t)(col0 + w * 32 + sr) * K + sg;

  f32x4 acc[4][4] = {};

  for (int k0 = 0; k0 < K; k0 += 64) {
    __syncthreads();
#pragma unroll
    for (int i = 0; i < 4; ++i) {
      gl2lds16(Ab + (size_t)(i * 8) * K + k0, &As[(w * 32 + i * 8) * 64]);
      gl2lds16(Bb + (size_t)(i * 8) * K + k0, &Bs[(w * 32 + i * 8) * 64]);
    }
    __syncthreads();
#pragma unroll
    for (int ks = 0; ks < 2; ++ks) {
      const int kg = ((ks * 4 + quad) ^ (l16 & 7)) * 8;
      bf16x8 af[4], bfr[4];
#pragma unroll
      for (int mt = 0; mt < 4; ++mt)
        af[mt] = *(const bf16x8*)(&As[(wm * 64 + mt * 16 + l16) * 64 + kg]);
#pragma unroll
      for (int nt = 0; nt < 4; ++nt)
        bfr[nt] = *(const bf16x8*)(&Bs[(wn * 64 + nt * 16 + l16) * 64 + kg]);
#pragma unroll
      for (int mt = 0; mt < 4; ++mt)
#pragma unroll
        for (int nt = 0; nt < 4; ++nt)
          acc[mt][nt] = MFMA16(af[mt], bfr[nt], acc[mt][nt]);
    }
  }

#pragma unroll
  for (int mt = 0; mt < 4; ++mt) {
#pragma unroll
    for (int nt = 0; nt < 4; ++nt) {
      const int col = col0 + wn * 64 + nt * 16 + l16;
      const float bv4 = bias[col];
      const int rowb = row0 + wm * 64 + mt * 16 + quad * 4;
      if (z != 0) {          // transposed scatter: [b,h,hd,s], b64 over s
        const int b = rowb >> 11, s = rowb & (Sn - 1);
        const int h = col >> 6, hd = col & 63;
        us4 pk;
#pragma unroll
        for (int r = 0; r < 4; ++r) pk[r] = f2bf(acc[mt][nt][r] + bv4);
        *(us4*)(Cp + ((size_t)((b * Hn + h) * HDn + hd)) * Sn + s) = pk;
      } else {               // Q scatter: [b,h,s,hd]
#pragma unroll
        for (int r = 0; r < 4; ++r) {
          const int row = rowb + r;
          const int b = row >> 11, s = row & (Sn - 1);
          const int h = col >> 6, hd = col & 63;
          Cp[(((size_t)(b * Hn + h) * Sn + s) << 6) + hd] = f2bf(acc[mt][nt][r] + bv4);
        }
      }
    }
  }
}

// Final projection: C[M,N] f32 = A[M,K]bf16 @ W[N,K]^T + bias
__global__ __launch_bounds__(256)
void gemm_out(const ushort_t* __restrict__ A, const ushort_t* __restrict__ Wt,
              const float* __restrict__ bias, float* __restrict__ Cp) {
  constexpr int K = 1024;
  __shared__ __align__(16) ushort_t As[128 * 64];
  __shared__ __align__(16) ushort_t Bs[128 * 64];

  const int tid = threadIdx.x;
  const int lane = tid & 63, w = tid >> 6;
  const int quad = lane >> 4, l16 = lane & 15;
  const int wm = w >> 1, wn = w & 1;
  const int row0 = blockIdx.y * 128;
  const int col0 = blockIdx.x * 128;

  const int sr = lane >> 3;
  const int sg = ((lane & 7) ^ (sr & 7)) * 8;
  const ushort_t* Ab = A  + (size_t)(row0 + w * 32 + sr) * K + sg;
  const ushort_t* Bb = Wt + (size_t)(col0 + w * 32 + sr) * K + sg;

  f32x4 acc[4][4] = {};

  for (int k0 = 0; k0 < K; k0 += 64) {
    __syncthreads();
#pragma unroll
    for (int i = 0; i < 4; ++i) {
      gl2lds16(Ab + (size_t)(i * 8) * K + k0, &As[(w * 32 + i * 8) * 64]);
      gl2lds16(Bb + (size_t)(i * 8) * K + k0, &Bs[(w * 32 + i * 8) * 64]);
    }
    __syncthreads();
#pragma unroll
    for (int ks = 0; ks < 2; ++ks) {
      const int kg = ((ks * 4 + quad) ^ (l16 & 7)) * 8;
      bf16x8 af[4], bfr[4];
#pragma unroll
      for (int mt = 0; mt < 4; ++mt)
        af[mt] = *(const bf16x8*)(&As[(wm * 64 + mt * 16 + l16) * 64 + kg]);
#pragma unroll
      for (int nt = 0; nt < 4; ++nt)
        bfr[nt] = *(const bf16x8*)(&Bs[(wn * 64 + nt * 16 + l16) * 64 + kg]);
#pragma unroll
      for (int mt = 0; mt < 4; ++mt)
#pragma unroll
        for (int nt = 0; nt < 4; ++nt)
          acc[mt][nt] = MFMA16(af[mt], bfr[nt], acc[mt][nt]);
    }
  }

#pragma unroll
  for (int mt = 0; mt < 4; ++mt)
#pragma unroll
    for (int nt = 0; nt < 4; ++nt) {
      const int col = col0 + wn * 64 + nt * 16 + l16;
      const float bv = bias[col];
      const int rowb = row0 + wm * 64 + mt * 16 + quad * 4;
#pragma unroll
      for (int r = 0; r < 4; ++r)
        Cp[(size_t)(rowb + r) * 1024 + col] = acc[mt][nt][r] + bv;
    }
}

// Prefix kernel (double-buffered, fused V-rowsum/suffix):
// Z'_qt[n_v][d_k] = (1/8)*sum_{k < qt*64} K[k][d_k]*V[k][n_v]   (bf16)
// suffV[bh][t][n] = sum_{k >= (t+1)*64} V[bh][k][n]             (f32)
__global__ __launch_bounds__(256)
void prefixz(const ushort_t* __restrict__ Kt, const ushort_t* __restrict__ Vt,
             ushort_t* __restrict__ Zp, float* __restrict__ suffV) {
  __shared__ __align__(16) ushort_t Kts[2][4096];
  __shared__ __align__(16) ushort_t Vts[2][4096];
  __shared__ float tsum[32 * 64];
  const int tid = threadIdx.x, lane = tid & 63, w = tid >> 6;
  const int quad = lane >> 4, l16 = lane & 15;
  const int bh = blockIdx.x;
  const ushort_t* Ktb = Kt + (size_t)bh * HDn * Sn;
  const ushort_t* Vtb = Vt + (size_t)bh * HDn * Sn;

  const int sr = lane >> 3;
  const int sg = ((lane & 7) ^ (sr & 7)) * 8;

  for (int i = tid; i < 2048; i += 256) tsum[i] = 0.f;

  // stage tile 0 into buf 0
#pragma unroll
  for (int c = 0; c < 2; ++c) {
    const int row = w * 16 + c * 8;
    gl2lds16(Ktb + (size_t)(row + sr) * Sn + sg, &Kts[0][row * 64]);
    gl2lds16(Vtb + (size_t)(row + sr) * Sn + sg, &Vts[0][row * 64]);
  }

  f32x4 zacc[4] = {};   // wave w: d_k rows w*16+quad*4+r, n_v cols nt*16+l16

  for (int t = 0; t < 32; ++t) {
    const int cur = t & 1;
    __syncthreads();                    // drains staging of buf[cur]
    if (t < 31) {                       // prefetch t+1 into other buffer
#pragma unroll
      for (int c = 0; c < 2; ++c) {
        const int row = w * 16 + c * 8;
        gl2lds16(Ktb + (size_t)(row + sr) * Sn + (t + 1) * 64 + sg, &Kts[1 - cur][row * 64]);
        gl2lds16(Vtb + (size_t)(row + sr) * Sn + (t + 1) * 64 + sg, &Vts[1 - cur][row * 64]);
      }
    }
    // store Z for qt=t (prefix over tiles 0..t-1), then accumulate G_t
    ushort_t* zd = Zp + (size_t)(bh * 32 + t) * 4096;
#pragma unroll
    for (int nt = 0; nt < 4; ++nt) {
      us4 pk;
#pragma unroll
      for (int r = 0; r < 4; ++r) pk[r] = f2bf(SCALE * zacc[nt][r]);
      *(us4*)(zd + (nt * 16 + l16) * 64 + w * 16 + quad * 4) = pk;
    }
    if (t < 31) {
#pragma unroll
      for (int ks = 0; ks < 2; ++ks) {
        const int kg = ((ks * 4 + quad) ^ (l16 & 7)) * 8;
        bf16x8 ak = *(const bf16x8*)(&Kts[cur][(w * 16 + l16) * 64 + kg]);
#pragma unroll
        for (int nt = 0; nt < 4; ++nt) {
          bf16x8 bv8 = *(const bf16x8*)(&Vts[cur][(nt * 16 + l16) * 64 + kg]);
          zacc[nt] = MFMA16(ak, bv8, zacc[nt]);
        }
      }
    }
    // V row partial sums for this tile: thread (n = tid&63, j = tid>>6)
    {
      const int n = tid & 63, j = tid >> 6;
      float p = 0.f;
#pragma unroll
      for (int gg2 = 0; gg2 < 2; ++gg2) {
        const int g = 2 * j + gg2;
        union { uint4 v; ushort_t u[8]; } c;
        c.v = *(const uint4*)(&Vts[cur][n * 64 + ((g ^ (n & 7)) << 3)]);
#pragma unroll
        for (int e = 0; e < 8; ++e) p += bf2f(c.u[e]);
      }
      atomicAdd(&tsum[t * 64 + n], p);
    }
  }
  __syncthreads();
  if (tid < 64) {
    float acc = 0.f;
    for (int t = 31; t >= 0; --t) {
      suffV[(size_t)(bh * 32 + t) * 64 + tid] = acc;
      acc += tsum[t * 64 + tid];
    }
  }
}

// One-shot attention, 4 q-tiles per block, double-buffered staging.
// Per q-tile: O^T = Z'·Q^T + V_d^T·S_d^T  - 1e9*suffV (analytic masked tail).
__global__ __launch_bounds__(256)
void attn_kernel(const ushort_t* __restrict__ Q, const ushort_t* __restrict__ Kt,
                 const ushort_t* __restrict__ Vt, const ushort_t* __restrict__ Zp,
                 const float* __restrict__ suffV, ushort_t* __restrict__ O) {
  __shared__ __align__(16) ushort_t Qs[2][4096];
  __shared__ __align__(16) ushort_t Vts[2][4096];
  __shared__ __align__(16) ushort_t Zs[2][4096];
  __shared__ __align__(16) ushort_t Ks[2][4096];
  __shared__ __align__(16) ushort_t Ss[64][72];

  const int tid = threadIdx.x, lane = tid & 63, w = tid >> 6;
  const int quad = lane >> 4, l16 = lane & 15;
  const int bh = blockIdx.y;
  const int qtb = blockIdx.x * 4;
  const int b = bh >> 4, h = bh & 15;
  const ushort_t* Qb  = Q  + (size_t)bh * Sn * HDn;
  const ushort_t* Ktb = Kt + (size_t)bh * HDn * Sn;
  const ushort_t* Vtb = Vt + (size_t)bh * HDn * Sn;

  const int sr = lane >> 3;
  const int sg = ((lane & 7) ^ (sr & 7)) * 8;
  const int q8 = lane & 7, h8 = lane >> 3;

  uint4 kv[2];
  // prologue: stage qt0 into buf 0
  {
    const int q0 = qtb * 64;
    const ushort_t* Zb = Zp + (size_t)(bh * 32 + qtb) * 4096;
#pragma unroll
    for (int c = 0; c < 2; ++c) {
      const int row = w * 16 + c * 8;
      gl2lds16(Qb + (size_t)(q0 + row + sr) * HDn + sg, &Qs[0][row * 64]);
      gl2lds16(Vtb + (size_t)(row + sr) * Sn + q0 + sg, &Vts[0][row * 64]);
      gl2lds16(Zb + (size_t)(row + sr) * 64 + sg, &Zs[0][row * 64]);
      kv[c] = *(const uint4*)(Ktb + (size_t)(w * 16 + c * 8 + h8) * Sn + q0 + q8 * 8);
    }
  }

  for (int i = 0; i < 4; ++i) {
    const int cur = i & 1;
    const int qt = qtb + i, q0 = qt * 64;

    // transpose-write diagonal K tile (regs -> Ks[cur], rotated+swizzled)
#pragma unroll
    for (int c = 0; c < 2; ++c) {
      const int hd = w * 16 + c * 8 + h8;
      const int G = hd >> 3;
      const ushort_t* ku = (const ushort_t*)&kv[c];
#pragma unroll
      for (int j = 0; j < 8; ++j) {
        const int e = (j + q8) & 7;
        const int s = q8 * 8 + e;
        Ks[cur][s * 64 + ((G ^ e) << 3) + (hd & 7)] = ku[e];
      }
    }
    __syncthreads();   // staging+transpose of buf[cur] done; compute i-1 done

    if (i < 3) {       // prefetch qt+1 into other buffer (overlaps compute)
      const int q1 = (qt + 1) * 64;
      const ushort_t* Zb = Zp + (size_t)(bh * 32 + qt + 1) * 4096;
#pragma unroll
      for (int c = 0; c < 2; ++c) {
        const int row = w * 16 + c * 8;
        gl2lds16(Qb + (size_t)(q1 + row + sr) * HDn + sg, &Qs[1 - cur][row * 64]);
        gl2lds16(Vtb + (size_t)(row + sr) * Sn + q1 + sg, &Vts[1 - cur][row * 64]);
        gl2lds16(Zb + (size_t)(row + sr) * 64 + sg, &Zs[1 - cur][row * 64]);
        kv[c] = *(const uint4*)(Ktb + (size_t)(w * 16 + c * 8 + h8) * Sn + q1 + q8 * 8);
      }
    }

    // ---- compute q-tile qt from buf[cur] ----
    bf16x8 bq[2];
#pragma unroll
    for (int ks = 0; ks < 2; ++ks)
      bq[ks] = *(const bf16x8*)(&Qs[cur][(w * 16 + l16) * 64 + (((ks * 4 + quad) ^ (l16 & 7)) << 3)]);

    f32x4 oacc[4] = {};
#pragma unroll
    for (int ks = 0; ks < 2; ++ks) {        // prefix: O^T += Z' · Q^T
      const int kg = ((ks * 4 + quad) ^ (l16 & 7)) * 8;
#pragma unroll
      for (int nt = 0; nt < 4; ++nt) {
        bf16x8 az = *(const bf16x8*)(&Zs[cur][(nt * 16 + l16) * 64 + kg]);
        oacc[nt] = MFMA16(az, bq[ks], oacc[nt]);
      }
    }
    f32x4 sacc[4] = {};
#pragma unroll
    for (int ks = 0; ks < 2; ++ks) {        // diagonal: S^T = K_d · Q^T
      const int kg = ((ks * 4 + quad) ^ (l16 & 7)) * 8;
#pragma unroll
      for (int nt = 0; nt < 4; ++nt) {
        bf16x8 ak = *(const bf16x8*)(&Ks[cur][(nt * 16 + l16) * 64 + kg]);
        sacc[nt] = MFMA16(ak, bq[ks], sacc[nt]);
      }
    }
    const int qrel = w * 16 + l16;          // mask + scale -> Ss (b64, intra-wave)
#pragma unroll
    for (int nt = 0; nt < 4; ++nt) {
      const int kb = nt * 16 + quad * 4;
      us4 pk;
#pragma unroll
      for (int r = 0; r < 4; ++r) {
        float val = (kb + r > qrel) ? NEG : sacc[nt][r] * SCALE;
        pk[r] = f2bf(val);
      }
      *(us4*)(&Ss[qrel][kb]) = pk;
    }
#pragma unroll
    for (int ks = 0; ks < 2; ++ks) {        // O^T += V_d^T · S_d^T
      bf16x8 bs = *(const bf16x8*)(&Ss[qrel][ks * 32 + quad * 8]);
#pragma unroll
      for (int nt = 0; nt < 4; ++nt) {
        bf16x8 av = *(const bf16x8*)(&Vts[cur][(nt * 16 + l16) * 64 + (((ks * 4 + quad) ^ (l16 & 7)) << 3)]);
        oacc[nt] = MFMA16(av, bs, oacc[nt]);
      }
    }

    // masked tail + store O[b,s,d] (b64 over n)
    const float* sv = suffV + (size_t)(bh * 32 + qt) * 64;
    const int s = q0 + w * 16 + l16;
#pragma unroll
    for (int nt = 0; nt < 4; ++nt) {
      const int nb = nt * 16 + quad * 4;
      float4 s4 = *(const float4*)(sv + nb);
      us4 pk;
      pk[0] = f2bf(oacc[nt][0] + NEG * s4.x);
      pk[1] = f2bf(oacc[nt][1] + NEG * s4.y);
      pk[2] = f2bf(oacc[nt][2] + NEG * s4.z);
      pk[3] = f2bf(oacc[nt][3] + NEG * s4.w);
      *(us4*)(&O[((size_t)(b * Sn + s)) * Dn + h * 64 + nb]) = pk;
    }
  }
}

extern "C" void kernel_launch(void* const* d_in, const int* in_sizes, int n_in,
                              void* d_out, int out_size, void* d_ws, size_t ws_size,
                              hipStream_t stream) {
  const float* Xq = (const float*)d_in[0];
  const float* Xk = (const float*)d_in[1];
  const float* Xv = (const float*)d_in[2];
  // d_in[3]: causal mask (int32) — tril, handled analytically
  const float* Wq = (const float*)d_in[4];
  const float* bq = (const float*)d_in[5];
  const float* Wk = (const float*)d_in[6];
  const float* bk = (const float*)d_in[7];
  const float* Wv = (const float*)d_in[8];
  const float* bv = (const float*)d_in[9];
  const float* Wo = (const float*)d_in[10];
  const float* bo = (const float*)d_in[11];

  // ws (MiB): [0,48) Xb(3) | [48,56) Wb(4) | [56,72) Q | [72,88) Kt |
  // [88,104) Vt | [104,120) Z | [120,136) O | [136,136.5) suffV  (d_ws=256MiB)
  constexpr size_t MiB = 1024 * 1024;
  char* ws = (char*)d_ws;
  ushort_t* Xb  = (ushort_t*)(ws);
  ushort_t* Wb  = (ushort_t*)(ws + 48 * MiB);
  ushort_t* Qb  = (ushort_t*)(ws + 56 * MiB);
  ushort_t* Ktb = (ushort_t*)(ws + 72 * MiB);
  ushort_t* Vtb = (ushort_t*)(ws + 88 * MiB);
  ushort_t* Zp  = (ushort_t*)(ws + 104 * MiB);
  ushort_t* Ob  = (ushort_t*)(ws + 120 * MiB);
  float*    sV  = (float*)   (ws + 136 * MiB);

  cvt_all<<<14336, 256, 0, stream>>>(Xq, Xk, Xv, Wq, Wk, Wv, Wo, Xb, Wb);
  gemm_qkv<<<dim3(8, 64, 3), 256, 0, stream>>>(Xb, Wb, bq, bk, bv, Qb, Ktb, Vtb);
  prefixz<<<64, 256, 0, stream>>>(Ktb, Vtb, Zp, sV);
  attn_kernel<<<dim3(8, 64), 256, 0, stream>>>(Qb, Ktb, Vtb, Zp, sV, Ob);
  gemm_out<<<dim3(8, 64), 256, 0, stream>>>(Ob, Wb + (size_t)3 * 1048576, bo,
                                            (float*)d_out);
}

// Round 6
// 320.826 us; speedup vs baseline: 2.4343x; 1.0301x over previous
//
#include <hip/hip_runtime.h>
#include <stdint.h>

typedef unsigned short ushort_t;
typedef __bf16 bf16x8 __attribute__((ext_vector_type(8)));
typedef float f32x4 __attribute__((ext_vector_type(4)));
typedef ushort_t us4 __attribute__((ext_vector_type(4)));

#define MFMA16(a, b, c) __builtin_amdgcn_mfma_f32_16x16x32_bf16((a), (b), (c), 0, 0, 0)

constexpr int Bn = 4, Sn = 2048, Dn = 1024, Hn = 16, HDn = 64;
constexpr float SCALE = 0.125f;   // 1/sqrt(64)
constexpr float NEG = -1e9f;

__device__ __forceinline__ float bf2f(ushort_t u) {
  unsigned x = ((unsigned)u) << 16;
  return __builtin_bit_cast(float, x);
}
__device__ __forceinline__ ushort_t f2bf(float f) {
  unsigned x = __builtin_bit_cast(unsigned, f);
  x = x + 0x7FFFu + ((x >> 16) & 1u);   // RNE
  return (ushort_t)(x >> 16);
}
__device__ __forceinline__ uint4 ld8_f32_bf16(const float* __restrict__ p) {
  float4 a = *(const float4*)p;
  float4 b = *(const float4*)(p + 4);
  union { ushort_t u[8]; uint4 v; } r;
  r.u[0] = f2bf(a.x); r.u[1] = f2bf(a.y); r.u[2] = f2bf(a.z); r.u[3] = f2bf(a.w);
  r.u[4] = f2bf(b.x); r.u[5] = f2bf(b.y); r.u[6] = f2bf(b.z); r.u[7] = f2bf(b.w);
  return r.v;
}
// async global->LDS, 16B per lane; LDS dest = wave-uniform base + lane*16
__device__ __forceinline__ void gl2lds16(const void* g, void* l) {
  __builtin_amdgcn_global_load_lds(
      (__attribute__((address_space(1))) void*)g,
      (__attribute__((address_space(3))) void*)l, 16, 0, 0);
}

// One-shot conversion of all f32 inputs to bf16: 3 X (4096 blocks each) then
// 4 W (512 blocks each). Xd: 3x8388608 elems contiguous; Wd: 4x1048576.
__global__ __launch_bounds__(256)
void cvt_all(const float* __restrict__ xq, const float* __restrict__ xk,
             const float* __restrict__ xv, const float* __restrict__ wq,
             const float* __restrict__ wk, const float* __restrict__ wv,
             const float* __restrict__ wo, ushort_t* __restrict__ Xd,
             ushort_t* __restrict__ Wd) {
  const int bid = blockIdx.x;
  if (bid < 12288) {
    const int which = bid >> 12;
    const float* s = which == 0 ? xq : which == 1 ? xk : xv;
    size_t i = ((size_t)(bid & 4095) * 256 + threadIdx.x) * 8;
    *(uint4*)(Xd + (size_t)which * 8388608 + i) = ld8_f32_bf16(s + i);
  } else {
    const int wb = bid - 12288, which = wb >> 9;
    const float* s = which == 0 ? wq : which == 1 ? wk : which == 2 ? wv : wo;
    size_t i = ((size_t)(wb & 511) * 256 + threadIdx.x) * 8;
    *(uint4*)(Wd + (size_t)which * 1048576 + i) = ld8_f32_bf16(s + i);
  }
}

// Fused Q/K/V projections: z = 0/1/2 selects X, W, bias, dst, epilogue.
// Grid (x=row-block, y=col-block): blocks sharing an A row-tile have linear
// IDs spaced 64 (≡ same mod 8) -> same XCD -> row-tile fetched once per L2.
// z=0: Q scatter [B,H,S,HD] b16. z=1,2: transposed scatter [B,H,HD,S] b64.
__global__ __launch_bounds__(256, 4)
void gemm_qkv(const ushort_t* __restrict__ Xb, const ushort_t* __restrict__ Wb,
              const float* __restrict__ bq, const float* __restrict__ bk,
              const float* __restrict__ bv, ushort_t* __restrict__ Qd,
              ushort_t* __restrict__ Ktd, ushort_t* __restrict__ Vtd) {
  constexpr int K = 1024;
  __shared__ __align__(16) ushort_t As[128 * 64];
  __shared__ __align__(16) ushort_t Bs[128 * 64];

  const int z = blockIdx.z;
  const ushort_t* A  = Xb + (size_t)z * 8388608;
  const ushort_t* Wt = Wb + (size_t)z * 1048576;
  const float* bias = z == 0 ? bq : z == 1 ? bk : bv;
  ushort_t* Cp = z == 0 ? Qd : z == 1 ? Ktd : Vtd;

  const int tid = threadIdx.x;
  const int lane = tid & 63, w = tid >> 6;
  const int quad = lane >> 4, l16 = lane & 15;
  const int wm = w >> 1, wn = w & 1;
  const int row0 = blockIdx.x * 128;   // x = row (XCD co-location)
  const int col0 = blockIdx.y * 128;   // y = col

  const int sr = lane >> 3;
  const int sg = ((lane & 7) ^ (sr & 7)) * 8;
  const ushort_t* Ab = A  + (size_t)(row0 + w * 32 + sr) * K + sg;
  const ushort_t* Bb = Wt + (size_t)(col0 + w * 32 + sr) * K + sg;

  f32x4 acc[4][4] = {};

  for (int k0 = 0; k0 < K; k0 += 64) {
    __syncthreads();
#pragma unroll
    for (int i = 0; i < 4; ++i) {
      gl2lds16(Ab + (size_t)(i * 8) * K + k0, &As[(w * 32 + i * 8) * 64]);
      gl2lds16(Bb + (size_t)(i * 8) * K + k0, &Bs[(w * 32 + i * 8) * 64]);
    }
    __syncthreads();
#pragma unroll
    for (int ks = 0; ks < 2; ++ks) {
      const int kg = ((ks * 4 + quad) ^ (l16 & 7)) * 8;
      bf16x8 af[4], bfr[4];
#pragma unroll
      for (int mt = 0; mt < 4; ++mt)
        af[mt] = *(const bf16x8*)(&As[(wm * 64 + mt * 16 + l16) * 64 + kg]);
#pragma unroll
      for (int nt = 0; nt < 4; ++nt)
        bfr[nt] = *(const bf16x8*)(&Bs[(wn * 64 + nt * 16 + l16) * 64 + kg]);
#pragma unroll
      for (int mt = 0; mt < 4; ++mt)
#pragma unroll
        for (int nt = 0; nt < 4; ++nt)
          acc[mt][nt] = MFMA16(af[mt], bfr[nt], acc[mt][nt]);
    }
  }

#pragma unroll
  for (int mt = 0; mt < 4; ++mt) {
#pragma unroll
    for (int nt = 0; nt < 4; ++nt) {
      const int col = col0 + wn * 64 + nt * 16 + l16;
      const float bv4 = bias[col];
      const int rowb = row0 + wm * 64 + mt * 16 + quad * 4;
      if (z != 0) {          // transposed scatter: [b,h,hd,s], b64 over s
        const int b = rowb >> 11, s = rowb & (Sn - 1);
        const int h = col >> 6, hd = col & 63;
        us4 pk;
#pragma unroll
        for (int r = 0; r < 4; ++r) pk[r] = f2bf(acc[mt][nt][r] + bv4);
        *(us4*)(Cp + ((size_t)((b * Hn + h) * HDn + hd)) * Sn + s) = pk;
      } else {               // Q scatter: [b,h,s,hd]
#pragma unroll
        for (int r = 0; r < 4; ++r) {
          const int row = rowb + r;
          const int b = row >> 11, s = row & (Sn - 1);
          const int h = col >> 6, hd = col & 63;
          Cp[(((size_t)(b * Hn + h) * Sn + s) << 6) + hd] = f2bf(acc[mt][nt][r] + bv4);
        }
      }
    }
  }
}

// Final projection: C[M,N] f32 = A[M,K]bf16 @ W[N,K]^T + bias.
// Grid (x=row, y=col) for the same XCD co-location as gemm_qkv.
__global__ __launch_bounds__(256, 4)
void gemm_out(const ushort_t* __restrict__ A, const ushort_t* __restrict__ Wt,
              const float* __restrict__ bias, float* __restrict__ Cp) {
  constexpr int K = 1024;
  __shared__ __align__(16) ushort_t As[128 * 64];
  __shared__ __align__(16) ushort_t Bs[128 * 64];

  const int tid = threadIdx.x;
  const int lane = tid & 63, w = tid >> 6;
  const int quad = lane >> 4, l16 = lane & 15;
  const int wm = w >> 1, wn = w & 1;
  const int row0 = blockIdx.x * 128;
  const int col0 = blockIdx.y * 128;

  const int sr = lane >> 3;
  const int sg = ((lane & 7) ^ (sr & 7)) * 8;
  const ushort_t* Ab = A  + (size_t)(row0 + w * 32 + sr) * K + sg;
  const ushort_t* Bb = Wt + (size_t)(col0 + w * 32 + sr) * K + sg;

  f32x4 acc[4][4] = {};

  for (int k0 = 0; k0 < K; k0 += 64) {
    __syncthreads();
#pragma unroll
    for (int i = 0; i < 4; ++i) {
      gl2lds16(Ab + (size_t)(i * 8) * K + k0, &As[(w * 32 + i * 8) * 64]);
      gl2lds16(Bb + (size_t)(i * 8) * K + k0, &Bs[(w * 32 + i * 8) * 64]);
    }
    __syncthreads();
#pragma unroll
    for (int ks = 0; ks < 2; ++ks) {
      const int kg = ((ks * 4 + quad) ^ (l16 & 7)) * 8;
      bf16x8 af[4], bfr[4];
#pragma unroll
      for (int mt = 0; mt < 4; ++mt)
        af[mt] = *(const bf16x8*)(&As[(wm * 64 + mt * 16 + l16) * 64 + kg]);
#pragma unroll
      for (int nt = 0; nt < 4; ++nt)
        bfr[nt] = *(const bf16x8*)(&Bs[(wn * 64 + nt * 16 + l16) * 64 + kg]);
#pragma unroll
      for (int mt = 0; mt < 4; ++mt)
#pragma unroll
        for (int nt = 0; nt < 4; ++nt)
          acc[mt][nt] = MFMA16(af[mt], bfr[nt], acc[mt][nt]);
    }
  }

#pragma unroll
  for (int mt = 0; mt < 4; ++mt)
#pragma unroll
    for (int nt = 0; nt < 4; ++nt) {
      const int col = col0 + wn * 64 + nt * 16 + l16;
      const float bv = bias[col];
      const int rowb = row0 + wm * 64 + mt * 16 + quad * 4;
#pragma unroll
      for (int r = 0; r < 4; ++r)
        Cp[(size_t)(rowb + r) * 1024 + col] = acc[mt][nt][r] + bv;
    }
}

// Prefix kernel (double-buffered, fused V-rowsum/suffix):
// Z'_qt[n_v][d_k] = (1/8)*sum_{k < qt*64} K[k][d_k]*V[k][n_v]   (bf16)
// suffV[bh][t][n] = sum_{k >= (t+1)*64} V[bh][k][n]             (f32)
__global__ __launch_bounds__(256)
void prefixz(const ushort_t* __restrict__ Kt, const ushort_t* __restrict__ Vt,
             ushort_t* __restrict__ Zp, float* __restrict__ suffV) {
  __shared__ __align__(16) ushort_t Kts[2][4096];
  __shared__ __align__(16) ushort_t Vts[2][4096];
  __shared__ float tsum[32 * 64];
  const int tid = threadIdx.x, lane = tid & 63, w = tid >> 6;
  const int quad = lane >> 4, l16 = lane & 15;
  const int bh = blockIdx.x;
  const ushort_t* Ktb = Kt + (size_t)bh * HDn * Sn;
  const ushort_t* Vtb = Vt + (size_t)bh * HDn * Sn;

  const int sr = lane >> 3;
  const int sg = ((lane & 7) ^ (sr & 7)) * 8;

  for (int i = tid; i < 2048; i += 256) tsum[i] = 0.f;

  // stage tile 0 into buf 0
#pragma unroll
  for (int c = 0; c < 2; ++c) {
    const int row = w * 16 + c * 8;
    gl2lds16(Ktb + (size_t)(row + sr) * Sn + sg, &Kts[0][row * 64]);
    gl2lds16(Vtb + (size_t)(row + sr) * Sn + sg, &Vts[0][row * 64]);
  }

  f32x4 zacc[4] = {};   // wave w: d_k rows w*16+quad*4+r, n_v cols nt*16+l16

  for (int t = 0; t < 32; ++t) {
    const int cur = t & 1;
    __syncthreads();                    // drains staging of buf[cur]
    if (t < 31) {                       // prefetch t+1 into other buffer
#pragma unroll
      for (int c = 0; c < 2; ++c) {
        const int row = w * 16 + c * 8;
        gl2lds16(Ktb + (size_t)(row + sr) * Sn + (t + 1) * 64 + sg, &Kts[1 - cur][row * 64]);
        gl2lds16(Vtb + (size_t)(row + sr) * Sn + (t + 1) * 64 + sg, &Vts[1 - cur][row * 64]);
      }
    }
    // store Z for qt=t (prefix over tiles 0..t-1), then accumulate G_t
    ushort_t* zd = Zp + (size_t)(bh * 32 + t) * 4096;
#pragma unroll
    for (int nt = 0; nt < 4; ++nt) {
      us4 pk;
#pragma unroll
      for (int r = 0; r < 4; ++r) pk[r] = f2bf(SCALE * zacc[nt][r]);
      *(us4*)(zd + (nt * 16 + l16) * 64 + w * 16 + quad * 4) = pk;
    }
    if (t < 31) {
#pragma unroll
      for (int ks = 0; ks < 2; ++ks) {
        const int kg = ((ks * 4 + quad) ^ (l16 & 7)) * 8;
        bf16x8 ak = *(const bf16x8*)(&Kts[cur][(w * 16 + l16) * 64 + kg]);
#pragma unroll
        for (int nt = 0; nt < 4; ++nt) {
          bf16x8 bv8 = *(const bf16x8*)(&Vts[cur][(nt * 16 + l16) * 64 + kg]);
          zacc[nt] = MFMA16(ak, bv8, zacc[nt]);
        }
      }
    }
    // V row partial sums for this tile: thread (n = tid&63, j = tid>>6)
    {
      const int n = tid & 63, j = tid >> 6;
      float p = 0.f;
#pragma unroll
      for (int gg2 = 0; gg2 < 2; ++gg2) {
        const int g = 2 * j + gg2;
        union { uint4 v; ushort_t u[8]; } c;
        c.v = *(const uint4*)(&Vts[cur][n * 64 + ((g ^ (n & 7)) << 3)]);
#pragma unroll
        for (int e = 0; e < 8; ++e) p += bf2f(c.u[e]);
      }
      atomicAdd(&tsum[t * 64 + n], p);
    }
  }
  __syncthreads();
  if (tid < 64) {
    float acc = 0.f;
    for (int t = 31; t >= 0; --t) {
      suffV[(size_t)(bh * 32 + t) * 64 + tid] = acc;
      acc += tsum[t * 64 + tid];
    }
  }
}

// One-shot attention, 4 q-tiles per block, double-buffered staging.
// Grid (x=bh, y=qtb): same-bh blocks spaced 64 -> same XCD (Kt/Vt L2 reuse).
// Per q-tile: O^T = Z'·Q^T + V_d^T·S_d^T  - 1e9*suffV (analytic masked tail).
__global__ __launch_bounds__(256)
void attn_kernel(const ushort_t* __restrict__ Q, const ushort_t* __restrict__ Kt,
                 const ushort_t* __restrict__ Vt, const ushort_t* __restrict__ Zp,
                 const float* __restrict__ suffV, ushort_t* __restrict__ O) {
  __shared__ __align__(16) ushort_t Qs[2][4096];
  __shared__ __align__(16) ushort_t Vts[2][4096];
  __shared__ __align__(16) ushort_t Zs[2][4096];
  __shared__ __align__(16) ushort_t Ks[2][4096];
  __shared__ __align__(16) ushort_t Ss[64][72];

  const int tid = threadIdx.x, lane = tid & 63, w = tid >> 6;
  const int quad = lane >> 4, l16 = lane & 15;
  const int bh = blockIdx.x;
  const int qtb = blockIdx.y * 4;
  const int b = bh >> 4, h = bh & 15;
  const ushort_t* Qb  = Q  + (size_t)bh * Sn * HDn;
  const ushort_t* Ktb = Kt + (size_t)bh * HDn * Sn;
  const ushort_t* Vtb = Vt + (size_t)bh * HDn * Sn;

  const int sr = lane >> 3;
  const int sg = ((lane & 7) ^ (sr & 7)) * 8;
  const int q8 = lane & 7, h8 = lane >> 3;

  uint4 kv[2];
  // prologue: stage qt0 into buf 0
  {
    const int q0 = qtb * 64;
    const ushort_t* Zb = Zp + (size_t)(bh * 32 + qtb) * 4096;
#pragma unroll
    for (int c = 0; c < 2; ++c) {
      const int row = w * 16 + c * 8;
      gl2lds16(Qb + (size_t)(q0 + row + sr) * HDn + sg, &Qs[0][row * 64]);
      gl2lds16(Vtb + (size_t)(row + sr) * Sn + q0 + sg, &Vts[0][row * 64]);
      gl2lds16(Zb + (size_t)(row + sr) * 64 + sg, &Zs[0][row * 64]);
      kv[c] = *(const uint4*)(Ktb + (size_t)(w * 16 + c * 8 + h8) * Sn + q0 + q8 * 8);
    }
  }

  for (int i = 0; i < 4; ++i) {
    const int cur = i & 1;
    const int qt = qtb + i, q0 = qt * 64;

    // transpose-write diagonal K tile (regs -> Ks[cur], rotated+swizzled)
#pragma unroll
    for (int c = 0; c < 2; ++c) {
      const int hd = w * 16 + c * 8 + h8;
      const int G = hd >> 3;
      const ushort_t* ku = (const ushort_t*)&kv[c];
#pragma unroll
      for (int j = 0; j < 8; ++j) {
        const int e = (j + q8) & 7;
        const int s = q8 * 8 + e;
        Ks[cur][s * 64 + ((G ^ e) << 3) + (hd & 7)] = ku[e];
      }
    }
    __syncthreads();   // staging+transpose of buf[cur] done; compute i-1 done

    if (i < 3) {       // prefetch qt+1 into other buffer (overlaps compute)
      const int q1 = (qt + 1) * 64;
      const ushort_t* Zb = Zp + (size_t)(bh * 32 + qt + 1) * 4096;
#pragma unroll
      for (int c = 0; c < 2; ++c) {
        const int row = w * 16 + c * 8;
        gl2lds16(Qb + (size_t)(q1 + row + sr) * HDn + sg, &Qs[1 - cur][row * 64]);
        gl2lds16(Vtb + (size_t)(row + sr) * Sn + q1 + sg, &Vts[1 - cur][row * 64]);
        gl2lds16(Zb + (size_t)(row + sr) * 64 + sg, &Zs[1 - cur][row * 64]);
        kv[c] = *(const uint4*)(Ktb + (size_t)(w * 16 + c * 8 + h8) * Sn + q1 + q8 * 8);
      }
    }

    // ---- compute q-tile qt from buf[cur] ----
    bf16x8 bq[2];
#pragma unroll
    for (int ks = 0; ks < 2; ++ks)
      bq[ks] = *(const bf16x8*)(&Qs[cur][(w * 16 + l16) * 64 + (((ks * 4 + quad) ^ (l16 & 7)) << 3)]);

    f32x4 oacc[4] = {};
#pragma unroll
    for (int ks = 0; ks < 2; ++ks) {        // prefix: O^T += Z' · Q^T
      const int kg = ((ks * 4 + quad) ^ (l16 & 7)) * 8;
#pragma unroll
      for (int nt = 0; nt < 4; ++nt) {
        bf16x8 az = *(const bf16x8*)(&Zs[cur][(nt * 16 + l16) * 64 + kg]);
        oacc[nt] = MFMA16(az, bq[ks], oacc[nt]);
      }
    }
    f32x4 sacc[4] = {};
#pragma unroll
    for (int ks = 0; ks < 2; ++ks) {        // diagonal: S^T = K_d · Q^T
      const int kg = ((ks * 4 + quad) ^ (l16 & 7)) * 8;
#pragma unroll
      for (int nt = 0; nt < 4; ++nt) {
        bf16x8 ak = *(const bf16x8*)(&Ks[cur][(nt * 16 + l16) * 64 + kg]);
        sacc[nt] = MFMA16(ak, bq[ks], sacc[nt]);
      }
    }
    const int qrel = w * 16 + l16;          // mask + scale -> Ss (b64, intra-wave)
#pragma unroll
    for (int nt = 0; nt < 4; ++nt) {
      const int kb = nt * 16 + quad * 4;
      us4 pk;
#pragma unroll
      for (int r = 0; r < 4; ++r) {
        float val = (kb + r > qrel) ? NEG : sacc[nt][r] * SCALE;
        pk[r] = f2bf(val);
      }
      *(us4*)(&Ss[qrel][kb]) = pk;
    }
#pragma unroll
    for (int ks = 0; ks < 2; ++ks) {        // O^T += V_d^T · S_d^T
      bf16x8 bs = *(const bf16x8*)(&Ss[qrel][ks * 32 + quad * 8]);
#pragma unroll
      for (int nt = 0; nt < 4; ++nt) {
        bf16x8 av = *(const bf16x8*)(&Vts[cur][(nt * 16 + l16) * 64 + (((ks * 4 + quad) ^ (l16 & 7)) << 3)]);
        oacc[nt] = MFMA16(av, bs, oacc[nt]);
      }
    }

    // masked tail + store O[b,s,d] (b64 over n)
    const float* sv = suffV + (size_t)(bh * 32 + qt) * 64;
    const int s = q0 + w * 16 + l16;
#pragma unroll
    for (int nt = 0; nt < 4; ++nt) {
      const int nb = nt * 16 + quad * 4;
      float4 s4 = *(const float4*)(sv + nb);
      us4 pk;
      pk[0] = f2bf(oacc[nt][0] + NEG * s4.x);
      pk[1] = f2bf(oacc[nt][1] + NEG * s4.y);
      pk[2] = f2bf(oacc[nt][2] + NEG * s4.z);
      pk[3] = f2bf(oacc[nt][3] + NEG * s4.w);
      *(us4*)(&O[((size_t)(b * Sn + s)) * Dn + h * 64 + nb]) = pk;
    }
  }
}

extern "C" void kernel_launch(void* const* d_in, const int* in_sizes, int n_in,
                              void* d_out, int out_size, void* d_ws, size_t ws_size,
                              hipStream_t stream) {
  const float* Xq = (const float*)d_in[0];
  const float* Xk = (const float*)d_in[1];
  const float* Xv = (const float*)d_in[2];
  // d_in[3]: causal mask (int32) — tril, handled analytically
  const float* Wq = (const float*)d_in[4];
  const float* bq = (const float*)d_in[5];
  const float* Wk = (const float*)d_in[6];
  const float* bk = (const float*)d_in[7];
  const float* Wv = (const float*)d_in[8];
  const float* bv = (const float*)d_in[9];
  const float* Wo = (const float*)d_in[10];
  const float* bo = (const float*)d_in[11];

  // ws (MiB): [0,48) Xb(3) | [48,56) Wb(4) | [56,72) Q | [72,88) Kt |
  // [88,104) Vt | [104,120) Z | [120,136) O | [136,136.5) suffV  (d_ws=256MiB)
  constexpr size_t MiB = 1024 * 1024;
  char* ws = (char*)d_ws;
  ushort_t* Xb  = (ushort_t*)(ws);
  ushort_t* Wb  = (ushort_t*)(ws + 48 * MiB);
  ushort_t* Qb  = (ushort_t*)(ws + 56 * MiB);
  ushort_t* Ktb = (ushort_t*)(ws + 72 * MiB);
  ushort_t* Vtb = (ushort_t*)(ws + 88 * MiB);
  ushort_t* Zp  = (ushort_t*)(ws + 104 * MiB);
  ushort_t* Ob  = (ushort_t*)(ws + 120 * MiB);
  float*    sV  = (float*)   (ws + 136 * MiB);

  cvt_all<<<14336, 256, 0, stream>>>(Xq, Xk, Xv, Wq, Wk, Wv, Wo, Xb, Wb);
  gemm_qkv<<<dim3(64, 8, 3), 256, 0, stream>>>(Xb, Wb, bq, bk, bv, Qb, Ktb, Vtb);
  prefixz<<<64, 256, 0, stream>>>(Ktb, Vtb, Zp, sV);
  attn_kernel<<<dim3(64, 8), 256, 0, stream>>>(Qb, Ktb, Vtb, Zp, sV, Ob);
  gemm_out<<<dim3(64, 8), 256, 0, stream>>>(Ob, Wb + (size_t)3 * 1048576, bo,
                                            (float*)d_out);
}